// Round 1
// baseline (931.541 us; speedup 1.0000x reference)
//
#include <hip/hip_runtime.h>
#include <math.h>

#define N_ROWS 50000
#define DIM 512
#define BM 64
#define BN 128
#define BK 32
#define LDP 40  // padded LDS row stride in bf16 elems (40*2=80B, 16B aligned, breaks pow2 banks)

typedef __attribute__((ext_vector_type(8))) short short8;
typedef __attribute__((ext_vector_type(4))) float float4v;

__device__ inline unsigned short f2bf(float x) {
    union { float f; unsigned u; } v; v.f = x;
    unsigned r = v.u + 0x7fffu + ((v.u >> 16) & 1u);  // RNE
    return (unsigned short)(r >> 16);
}

__device__ inline short8 packv(float4v x, float4v y) {
    short8 r;
    r[0] = (short)f2bf(x[0]); r[1] = (short)f2bf(x[1]);
    r[2] = (short)f2bf(x[2]); r[3] = (short)f2bf(x[3]);
    r[4] = (short)f2bf(y[0]); r[5] = (short)f2bf(y[1]);
    r[6] = (short)f2bf(y[2]); r[7] = (short)f2bf(y[3]);
    return r;
}

__global__ void init_sums(float* sums) {
    if (threadIdx.x < 3) sums[threadIdx.x] = 0.0f;
}

__global__ __launch_bounds__(256, 2) void fused_mma(
    const float* __restrict__ img, const float* __restrict__ ph,
    const float* __restrict__ Ws,  const float* __restrict__ bs,
    const float* __restrict__ Wi,  const float* __restrict__ bi,
    const float* __restrict__ Wp,  const float* __restrict__ bp,
    float* __restrict__ out, float* __restrict__ sums)
{
    __shared__ __align__(16) unsigned short sA[3][BM][LDP];  // 0=img 1=ph 2=shared
    __shared__ __align__(16) unsigned short sB[3][BN][LDP];

    const int tid  = threadIdx.x;
    const int n0   = blockIdx.x * BM;
    const int e0   = blockIdx.y * BN;
    const int lane = tid & 63;
    const int wid  = tid >> 6;
    const int wm   = wid & 1;       // 32-row half
    const int wn   = wid >> 1;      // 64-col half
    const int l15  = lane & 15;
    const int quad = lane >> 4;

    // staging assignment: 256 threads cover 64 rows x 4 chunks of 8 elems
    const int arow   = tid >> 2;          // 0..63
    const int acol   = (tid & 3) * 8;     // 0,8,16,24
    const bool avalid = (n0 + arow) < N_ROWS;

    const float* Wmat[3] = { Wi, Wp, Ws };

    float4v acc[3][2][4];
#pragma unroll
    for (int m = 0; m < 3; ++m)
#pragma unroll
        for (int i = 0; i < 2; ++i)
#pragma unroll
            for (int j = 0; j < 4; ++j)
                acc[m][i][j] = (float4v){0.f, 0.f, 0.f, 0.f};

#pragma unroll 1
    for (int kb = 0; kb < DIM / BK; ++kb) {
        const int k0 = kb * BK;

        // ---- stage A (img, ph, shared) ----
        {
            short8 vi, vp, vs;
            if (avalid) {
                const float* pi = img + (size_t)(n0 + arow) * DIM + k0 + acol;
                const float* pp = ph  + (size_t)(n0 + arow) * DIM + k0 + acol;
                float4v i0 = *(const float4v*)pi,       i1 = *(const float4v*)(pi + 4);
                float4v p0 = *(const float4v*)pp,       p1 = *(const float4v*)(pp + 4);
                float4v s0 = 0.5f * (i0 + p0);
                float4v s1 = 0.5f * (i1 + p1);
                vi = packv(i0, i1); vp = packv(p0, p1); vs = packv(s0, s1);
            } else {
                vi = (short8){0,0,0,0,0,0,0,0}; vp = vi; vs = vi;
            }
            *(short8*)&sA[0][arow][acol] = vi;
            *(short8*)&sA[1][arow][acol] = vp;
            *(short8*)&sA[2][arow][acol] = vs;
        }

        // ---- stage B (W_img, W_ph, W_shared), rows always valid (512 = 4*128) ----
#pragma unroll
        for (int rep = 0; rep < 2; ++rep) {
            const int er = arow + rep * 64;
#pragma unroll
            for (int mat = 0; mat < 3; ++mat) {
                const float* pw = Wmat[mat] + (size_t)(e0 + er) * DIM + k0 + acol;
                float4v w0 = *(const float4v*)pw, w1 = *(const float4v*)(pw + 4);
                *(short8*)&sB[mat][er][acol] = packv(w0, w1);
            }
        }

        __syncthreads();

        // ---- MFMA: 3 matrices x 2 m-tiles x 4 n-tiles ----
#pragma unroll
        for (int mat = 0; mat < 3; ++mat) {
            short8 af[2], bfr[4];
#pragma unroll
            for (int i = 0; i < 2; ++i)
                af[i] = *(const short8*)&sA[mat][wm * 32 + i * 16 + l15][quad * 8];
#pragma unroll
            for (int j = 0; j < 4; ++j)
                bfr[j] = *(const short8*)&sB[mat][wn * 64 + j * 16 + l15][quad * 8];
#pragma unroll
            for (int i = 0; i < 2; ++i)
#pragma unroll
                for (int j = 0; j < 4; ++j)
                    acc[mat][i][j] = __builtin_amdgcn_mfma_f32_16x16x32_bf16(
                        af[i], bfr[j], acc[mat][i][j], 0, 0, 0);
        }

        __syncthreads();
    }

    // ---- epilogue: tanh + bias, joint write, squared sums ----
    float s_i = 0.f, s_p = 0.f, s_s = 0.f;
#pragma unroll
    for (int i = 0; i < 2; ++i) {
#pragma unroll
        for (int j = 0; j < 4; ++j) {
            const int c = e0 + wn * 64 + j * 16 + l15;
            const float bii = bi[c], bpp = bp[c], bss = bs[c];
            const int rbase = n0 + wm * 32 + i * 16 + quad * 4;
#pragma unroll
            for (int r = 0; r < 4; ++r) {
                const int nrow = rbase + r;
                const float ia = tanhf(acc[0][i][j][r] + bii);
                const float pa = tanhf(acc[1][i][j][r] + bpp);
                const float sa = tanhf(acc[2][i][j][r] + bss);
                if (nrow < N_ROWS) {
                    const size_t off = (size_t)nrow * DIM + c;
                    const float ie = img[off];
                    const float pe = ph[off];
                    const float se = 0.5f * (ie + pe);
                    out[off] = sa * se + ia * ie + pa * pe;
                    s_i += ia * ia; s_p += pa * pa; s_s += sa * sa;
                }
            }
        }
    }

    // wave reduce (64 lanes), then one atomic per wave per sum
#pragma unroll
    for (int off = 32; off > 0; off >>= 1) {
        s_i += __shfl_down(s_i, off);
        s_p += __shfl_down(s_p, off);
        s_s += __shfl_down(s_s, off);
    }
    if (lane == 0) {
        atomicAdd(&sums[0], s_i);
        atomicAdd(&sums[1], s_p);
        atomicAdd(&sums[2], s_s);
    }
}

__global__ void finalize(const float* __restrict__ sums, float* __restrict__ wout) {
    if (threadIdx.x == 0) {
        const float inv_sh = 1.0f / sums[2];
        const float is = sums[0] * inv_sh;
        const float ps = sums[1] * inv_sh;
        const float m  = fmaxf(is, ps);
        const float ei = expf(is - m), ep = expf(ps - m);
        const float inv = 1.0f / (ei + ep);
        wout[0] = ei * inv;
        wout[1] = ep * inv;
    }
}

extern "C" void kernel_launch(void* const* d_in, const int* in_sizes, int n_in,
                              void* d_out, int out_size, void* d_ws, size_t ws_size,
                              hipStream_t stream) {
    const float* img = (const float*)d_in[0];
    const float* ph  = (const float*)d_in[1];
    const float* Ws  = (const float*)d_in[2];
    const float* bs  = (const float*)d_in[3];
    const float* Wi  = (const float*)d_in[4];
    const float* bi  = (const float*)d_in[5];
    const float* Wp  = (const float*)d_in[6];
    const float* bp  = (const float*)d_in[7];
    float* out  = (float*)d_out;
    float* sums = (float*)d_ws;

    init_sums<<<1, 64, 0, stream>>>(sums);

    dim3 grid((N_ROWS + BM - 1) / BM, DIM / BN);
    fused_mma<<<grid, 256, 0, stream>>>(img, ph, Ws, bs, Wi, bi, Wp, bp, out, sums);

    finalize<<<1, 64, 0, stream>>>(sums, out + (size_t)N_ROWS * DIM);
}

// Round 2
// 848.343 us; speedup vs baseline: 1.0981x; 1.0981x over previous
//
#include <hip/hip_runtime.h>
#include <math.h>

#define N_ROWS 50000
#define DIM 512
#define NPAD 50048          // 391 * 128, padded row count for OOB-safe global_load_lds

// K2 tile
#define BM 128
#define BN 64
#define BK 32

typedef __attribute__((ext_vector_type(8))) short short8;
typedef __attribute__((ext_vector_type(4))) float float4v;

__device__ inline unsigned short f2bf(float x) {
    union { float f; unsigned u; } v; v.f = x;
    unsigned r = v.u + 0x7fffu + ((v.u >> 16) & 1u);  // RNE
    return (unsigned short)(r >> 16);
}

__device__ inline float bf2f(unsigned short u) {
    union { unsigned u; float f; } v; v.u = ((unsigned)u) << 16; return v.f;
}

__device__ inline short8 packv(float4v x, float4v y) {
    short8 r;
    r[0] = (short)f2bf(x[0]); r[1] = (short)f2bf(x[1]);
    r[2] = (short)f2bf(x[2]); r[3] = (short)f2bf(x[3]);
    r[4] = (short)f2bf(y[0]); r[5] = (short)f2bf(y[1]);
    r[6] = (short)f2bf(y[2]); r[7] = (short)f2bf(y[3]);
    return r;
}

// tanh via hw exp + rcp: ~7 VALU ops vs ~20+ for ocml tanhf. abs err ~1e-6.
__device__ inline float fast_tanh(float x) {
    float xc = fminf(fmaxf(x, -15.f), 15.f);
    float e = __expf(2.0f * xc);
    return 1.0f - 2.0f * __builtin_amdgcn_rcpf(e + 1.0f);
}

__device__ inline void async_ld16(const void* g, void* l) {
    __builtin_amdgcn_global_load_lds(
        (__attribute__((address_space(1))) void*)g,
        (__attribute__((address_space(3))) void*)l, 16, 0, 0);
}

__global__ void init_sums(float* sums) {
    if (threadIdx.x < 3) sums[threadIdx.x] = 0.0f;
}

// ---- K1: fp32 -> bf16 conversion of embeddings (+ shared = 0.5*(img+ph)) ----
__global__ __launch_bounds__(256) void convert_embed(
    const float* __restrict__ img, const float* __restrict__ ph,
    unsigned short* __restrict__ img_bf, unsigned short* __restrict__ ph_bf,
    unsigned short* __restrict__ sh_bf)
{
    const size_t idx = ((size_t)blockIdx.x * 256 + threadIdx.x) * 8;
    float4v i0 = *(const float4v*)(img + idx);
    float4v i1 = *(const float4v*)(img + idx + 4);
    float4v p0 = *(const float4v*)(ph + idx);
    float4v p1 = *(const float4v*)(ph + idx + 4);
    float4v s0 = 0.5f * (i0 + p0);
    float4v s1 = 0.5f * (i1 + p1);
    *(short8*)(img_bf + idx) = packv(i0, i1);
    *(short8*)(ph_bf + idx)  = packv(p0, p1);
    *(short8*)(sh_bf + idx)  = packv(s0, s1);
}

__global__ __launch_bounds__(256) void convert_w(
    const float* __restrict__ Wi, const float* __restrict__ Wp, const float* __restrict__ Ws,
    unsigned short* __restrict__ Wi_bf, unsigned short* __restrict__ Wp_bf,
    unsigned short* __restrict__ Ws_bf)
{
    const int t = blockIdx.x * 256 + threadIdx.x;   // 0..98303
    const int mat = t >> 15;                        // 32768 threads per matrix
    const size_t idx = (size_t)(t & 32767) * 8;
    const float* src = (mat == 0) ? Wi : ((mat == 1) ? Wp : Ws);
    unsigned short* dst = (mat == 0) ? Wi_bf : ((mat == 1) ? Wp_bf : Ws_bf);
    float4v a = *(const float4v*)(src + idx);
    float4v b = *(const float4v*)(src + idx + 4);
    *(short8*)(dst + idx) = packv(a, b);
}

// ---- K2: fused triple GEMM + tanh + joint combine + Frobenius sums ----
__global__ __launch_bounds__(256, 2) void fused_mma2(
    const unsigned short* __restrict__ img_bf, const unsigned short* __restrict__ ph_bf,
    const unsigned short* __restrict__ sh_bf,
    const unsigned short* __restrict__ Wi_bf, const unsigned short* __restrict__ Wp_bf,
    const unsigned short* __restrict__ Ws_bf,
    const float* __restrict__ bs, const float* __restrict__ bi, const float* __restrict__ bp,
    float* __restrict__ out, float* __restrict__ sums)
{
    // unpadded layout required: global_load_lds writes wave-uniform base + lane*16
    __shared__ __align__(16) unsigned short sA[3][BM][BK];  // 24 KB
    __shared__ __align__(16) unsigned short sB[3][BN][BK];  // 12 KB

    const int tid  = threadIdx.x;
    const int lane = tid & 63;
    const int wid  = tid >> 6;
    const int wm   = wid & 1;       // 64-row half
    const int wn   = wid >> 1;      // 32-col half
    const int l15  = lane & 15;
    const int quad = lane >> 4;

    const int e0 = blockIdx.x * BN;
    const int n0 = blockIdx.y * BM;

    const unsigned short* Amat[3] = { img_bf, ph_bf, sh_bf };
    const unsigned short* Bmat[3] = { Wi_bf, Wp_bf, Ws_bf };

    const int lrow = lane >> 2;        // 0..15 (row within 16-row chunk)
    const int lcol = (lane & 3) * 8;   // elem offset within 32-elem row

    float4v acc[3][4][2];
#pragma unroll
    for (int m = 0; m < 3; ++m)
#pragma unroll
        for (int i = 0; i < 4; ++i)
#pragma unroll
            for (int j = 0; j < 2; ++j)
                acc[m][i][j] = (float4v){0.f, 0.f, 0.f, 0.f};

#pragma unroll 1
    for (int kb = 0; kb < DIM / BK; ++kb) {
        const int k0 = kb * BK;

        // 36 wave-chunks of 1 KB (24 for A: 3 mats x 8, 12 for B: 3 mats x 4),
        // 9 per wave, DMA'd straight to LDS.
#pragma unroll
        for (int t = 0; t < 9; ++t) {
            const int c = wid * 9 + t;
            if (c < 24) {
                const int mat = c >> 3, sub = c & 7;
                const unsigned short* g =
                    Amat[mat] + (size_t)(n0 + sub * 16 + lrow) * DIM + k0 + lcol;
                async_ld16(g, &sA[mat][sub * 16][0]);
            } else {
                const int cc = c - 24;
                const int mat = cc >> 2, sub = cc & 3;
                const unsigned short* g =
                    Bmat[mat] + (size_t)(e0 + sub * 16 + lrow) * DIM + k0 + lcol;
                async_ld16(g, &sB[mat][sub * 16][0]);
            }
        }

        __syncthreads();

#pragma unroll
        for (int mat = 0; mat < 3; ++mat) {
            short8 a[4], b[2];
#pragma unroll
            for (int i = 0; i < 4; ++i)
                a[i] = *(const short8*)&sA[mat][wm * 64 + i * 16 + l15][quad * 8];
#pragma unroll
            for (int j = 0; j < 2; ++j)
                b[j] = *(const short8*)&sB[mat][wn * 32 + j * 16 + l15][quad * 8];
#pragma unroll
            for (int i = 0; i < 4; ++i)
#pragma unroll
                for (int j = 0; j < 2; ++j)
                    acc[mat][i][j] = __builtin_amdgcn_mfma_f32_16x16x32_bf16(
                        a[i], b[j], acc[mat][i][j], 0, 0, 0);
        }

        __syncthreads();
    }

    // ---- epilogue ----
    float s_i = 0.f, s_p = 0.f, s_s = 0.f;
#pragma unroll
    for (int i = 0; i < 4; ++i) {
#pragma unroll
        for (int j = 0; j < 2; ++j) {
            const int c = e0 + wn * 32 + j * 16 + l15;
            const float bii = bi[c], bpp = bp[c], bss = bs[c];
            const int rbase = n0 + wm * 64 + i * 16 + quad * 4;
#pragma unroll
            for (int r = 0; r < 4; ++r) {
                const int nrow = rbase + r;
                const float ia = fast_tanh(acc[0][i][j][r] + bii);
                const float pa = fast_tanh(acc[1][i][j][r] + bpp);
                const float sa = fast_tanh(acc[2][i][j][r] + bss);
                if (nrow < N_ROWS) {
                    const size_t off = (size_t)nrow * DIM + c;
                    const float ie = bf2f(img_bf[off]);
                    const float pe = bf2f(ph_bf[off]);
                    const float se = 0.5f * (ie + pe);
                    out[off] = sa * se + ia * ie + pa * pe;
                    s_i += ia * ia; s_p += pa * pa; s_s += sa * sa;
                }
            }
        }
    }

#pragma unroll
    for (int off = 32; off > 0; off >>= 1) {
        s_i += __shfl_down(s_i, off);
        s_p += __shfl_down(s_p, off);
        s_s += __shfl_down(s_s, off);
    }
    if (lane == 0) {
        atomicAdd(&sums[0], s_i);
        atomicAdd(&sums[1], s_p);
        atomicAdd(&sums[2], s_s);
    }
}

// ---- fallback (round-1 kernel) if ws too small ----
#define FLDP 40
__global__ __launch_bounds__(256, 2) void fused_fallback(
    const float* __restrict__ img, const float* __restrict__ ph,
    const float* __restrict__ Ws,  const float* __restrict__ bs,
    const float* __restrict__ Wi,  const float* __restrict__ bi,
    const float* __restrict__ Wp,  const float* __restrict__ bp,
    float* __restrict__ out, float* __restrict__ sums)
{
    __shared__ __align__(16) unsigned short sA[3][64][FLDP];
    __shared__ __align__(16) unsigned short sB[3][128][FLDP];
    const int tid = threadIdx.x;
    const int n0 = blockIdx.x * 64, e0 = blockIdx.y * 128;
    const int lane = tid & 63, wid = tid >> 6;
    const int wm = wid & 1, wn = wid >> 1;
    const int l15 = lane & 15, quad = lane >> 4;
    const int arow = tid >> 2, acol = (tid & 3) * 8;
    const bool avalid = (n0 + arow) < N_ROWS;
    const float* Wmat[3] = { Wi, Wp, Ws };
    float4v acc[3][2][4];
#pragma unroll
    for (int m = 0; m < 3; ++m)
#pragma unroll
        for (int i = 0; i < 2; ++i)
#pragma unroll
            for (int j = 0; j < 4; ++j) acc[m][i][j] = (float4v){0.f,0.f,0.f,0.f};
#pragma unroll 1
    for (int kb = 0; kb < 16; ++kb) {
        const int k0 = kb * 32;
        short8 vi, vp, vs;
        if (avalid) {
            const float* pi = img + (size_t)(n0 + arow) * DIM + k0 + acol;
            const float* pp = ph  + (size_t)(n0 + arow) * DIM + k0 + acol;
            float4v i0 = *(const float4v*)pi, i1 = *(const float4v*)(pi + 4);
            float4v p0 = *(const float4v*)pp, p1 = *(const float4v*)(pp + 4);
            vi = packv(i0, i1); vp = packv(p0, p1);
            vs = packv(0.5f*(i0+p0), 0.5f*(i1+p1));
        } else { vi = (short8){0,0,0,0,0,0,0,0}; vp = vi; vs = vi; }
        *(short8*)&sA[0][arow][acol] = vi;
        *(short8*)&sA[1][arow][acol] = vp;
        *(short8*)&sA[2][arow][acol] = vs;
#pragma unroll
        for (int rep = 0; rep < 2; ++rep) {
            const int er = arow + rep * 64;
#pragma unroll
            for (int mat = 0; mat < 3; ++mat) {
                const float* pw = Wmat[mat] + (size_t)(e0 + er) * DIM + k0 + acol;
                *(short8*)&sB[mat][er][acol] =
                    packv(*(const float4v*)pw, *(const float4v*)(pw + 4));
            }
        }
        __syncthreads();
#pragma unroll
        for (int mat = 0; mat < 3; ++mat) {
            short8 af[2], bfr[4];
#pragma unroll
            for (int i = 0; i < 2; ++i)
                af[i] = *(const short8*)&sA[mat][wm*32 + i*16 + l15][quad*8];
#pragma unroll
            for (int j = 0; j < 4; ++j)
                bfr[j] = *(const short8*)&sB[mat][wn*64 + j*16 + l15][quad*8];
#pragma unroll
            for (int i = 0; i < 2; ++i)
#pragma unroll
                for (int j = 0; j < 4; ++j)
                    acc[mat][i][j] = __builtin_amdgcn_mfma_f32_16x16x32_bf16(
                        af[i], bfr[j], acc[mat][i][j], 0, 0, 0);
        }
        __syncthreads();
    }
    float s_i = 0.f, s_p = 0.f, s_s = 0.f;
#pragma unroll
    for (int i = 0; i < 2; ++i)
#pragma unroll
        for (int j = 0; j < 4; ++j) {
            const int c = e0 + wn*64 + j*16 + l15;
            const float bii = bi[c], bpp = bp[c], bss = bs[c];
            const int rbase = n0 + wm*32 + i*16 + quad*4;
#pragma unroll
            for (int r = 0; r < 4; ++r) {
                const int nrow = rbase + r;
                const float ia = fast_tanh(acc[0][i][j][r] + bii);
                const float pa = fast_tanh(acc[1][i][j][r] + bpp);
                const float sa = fast_tanh(acc[2][i][j][r] + bss);
                if (nrow < N_ROWS) {
                    const size_t off = (size_t)nrow * DIM + c;
                    const float ie = img[off], pe = ph[off];
                    out[off] = sa * 0.5f*(ie+pe) + ia*ie + pa*pe;
                    s_i += ia*ia; s_p += pa*pa; s_s += sa*sa;
                }
            }
        }
#pragma unroll
    for (int off = 32; off > 0; off >>= 1) {
        s_i += __shfl_down(s_i, off);
        s_p += __shfl_down(s_p, off);
        s_s += __shfl_down(s_s, off);
    }
    if (lane == 0) {
        atomicAdd(&sums[0], s_i); atomicAdd(&sums[1], s_p); atomicAdd(&sums[2], s_s);
    }
}

__global__ void finalize(const float* __restrict__ sums, float* __restrict__ wout) {
    if (threadIdx.x == 0) {
        const float inv_sh = 1.0f / sums[2];
        const float is = sums[0] * inv_sh;
        const float ps = sums[1] * inv_sh;
        const float m  = fmaxf(is, ps);
        const float ei = expf(is - m), ep = expf(ps - m);
        const float inv = 1.0f / (ei + ep);
        wout[0] = ei * inv;
        wout[1] = ep * inv;
    }
}

extern "C" void kernel_launch(void* const* d_in, const int* in_sizes, int n_in,
                              void* d_out, int out_size, void* d_ws, size_t ws_size,
                              hipStream_t stream) {
    const float* img = (const float*)d_in[0];
    const float* ph  = (const float*)d_in[1];
    const float* Ws  = (const float*)d_in[2];
    const float* bs  = (const float*)d_in[3];
    const float* Wi  = (const float*)d_in[4];
    const float* bi  = (const float*)d_in[5];
    const float* Wp  = (const float*)d_in[6];
    const float* bp  = (const float*)d_in[7];
    float* out  = (float*)d_out;
    float* sums = (float*)d_ws;

    const size_t embed_elems = (size_t)NPAD * DIM;     // padded bf16 array
    const size_t w_elems = (size_t)DIM * DIM;
    const size_t ws_needed = 256 + 3 * embed_elems * 2 + 3 * w_elems * 2;

    init_sums<<<1, 64, 0, stream>>>(sums);

    if (ws_size >= ws_needed) {
        unsigned short* base  = (unsigned short*)((char*)d_ws + 256);
        unsigned short* img_bf = base;
        unsigned short* ph_bf  = img_bf + embed_elems;
        unsigned short* sh_bf  = ph_bf + embed_elems;
        unsigned short* Wi_bf  = sh_bf + embed_elems;
        unsigned short* Wp_bf  = Wi_bf + w_elems;
        unsigned short* Ws_bf  = Wp_bf + w_elems;

        convert_embed<<<(N_ROWS * DIM) / 2048, 256, 0, stream>>>(img, ph, img_bf, ph_bf, sh_bf);
        convert_w<<<384, 256, 0, stream>>>(Wi, Wp, Ws, Wi_bf, Wp_bf, Ws_bf);

        dim3 grid(DIM / BN, (N_ROWS + BM - 1) / BM);   // e-tiles fast, row-tiles slow
        fused_mma2<<<grid, 256, 0, stream>>>(img_bf, ph_bf, sh_bf, Wi_bf, Wp_bf, Ws_bf,
                                             bs, bi, bp, out, sums);
    } else {
        dim3 grid((N_ROWS + 63) / 64, DIM / 128);
        fused_fallback<<<grid, 256, 0, stream>>>(img, ph, Ws, bs, Wi, bi, Wp, bp, out, sums);
    }

    finalize<<<1, 64, 0, stream>>>(sums, out + (size_t)N_ROWS * DIM);
}

// Round 3
// 809.050 us; speedup vs baseline: 1.1514x; 1.0486x over previous
//
#include <hip/hip_runtime.h>
#include <math.h>

#define N_ROWS 50000
#define DIM 512
#define NPAD 50048          // 391 * 128, padded row count for OOB-safe global_load_lds

// K2 tile
#define BM 128
#define BN 64
#define BK 32
#define N_STRIPS 391        // ceil(50000/128)
#define STRIPS_PER_XCD 49   // ceil(391/8)

typedef __attribute__((ext_vector_type(8))) short short8;
typedef __attribute__((ext_vector_type(4))) float float4v;

__device__ inline unsigned short f2bf(float x) {
    union { float f; unsigned u; } v; v.f = x;
    unsigned r = v.u + 0x7fffu + ((v.u >> 16) & 1u);  // RNE
    return (unsigned short)(r >> 16);
}

__device__ inline float bf2f(unsigned short u) {
    union { unsigned u; float f; } v; v.u = ((unsigned)u) << 16; return v.f;
}

__device__ inline short8 packv(float4v x, float4v y) {
    short8 r;
    r[0] = (short)f2bf(x[0]); r[1] = (short)f2bf(x[1]);
    r[2] = (short)f2bf(x[2]); r[3] = (short)f2bf(x[3]);
    r[4] = (short)f2bf(y[0]); r[5] = (short)f2bf(y[1]);
    r[6] = (short)f2bf(y[2]); r[7] = (short)f2bf(y[3]);
    return r;
}

// tanh via hw exp + rcp: ~7 VALU ops vs ~20+ for ocml tanhf.
__device__ inline float fast_tanh(float x) {
    float xc = fminf(fmaxf(x, -15.f), 15.f);
    float e = __expf(2.0f * xc);
    return 1.0f - 2.0f * __builtin_amdgcn_rcpf(e + 1.0f);
}

__device__ inline void async_ld16(const void* g, void* l) {
    __builtin_amdgcn_global_load_lds(
        (__attribute__((address_space(1))) void*)g,
        (__attribute__((address_space(3))) void*)l, 16, 0, 0);
}

// ---- K1: one streaming pass: fp32->bf16 for embeddings (+shared), W mats, sums=0 ----
#define EMBED_BLOCKS 12512   // NPAD*512/8/256
#define W_BLOCKS 384         // 3*512*512/8/256
__global__ __launch_bounds__(256) void convert_all(
    const float* __restrict__ img, const float* __restrict__ ph,
    const float* __restrict__ Wi, const float* __restrict__ Wp, const float* __restrict__ Ws,
    unsigned short* __restrict__ img_bf, unsigned short* __restrict__ ph_bf,
    unsigned short* __restrict__ sh_bf,
    unsigned short* __restrict__ Wi_bf, unsigned short* __restrict__ Wp_bf,
    unsigned short* __restrict__ Ws_bf,
    float* __restrict__ sums)
{
    const int bid = blockIdx.x;
    if (bid == 0 && threadIdx.x < 3) sums[threadIdx.x] = 0.0f;

    if (bid < EMBED_BLOCKS) {
        const size_t idx = ((size_t)bid * 256 + threadIdx.x) * 8;
        const int row = (int)(idx >> 9);
        if (row < N_ROWS) {
            float4v i0 = *(const float4v*)(img + idx);
            float4v i1 = *(const float4v*)(img + idx + 4);
            float4v p0 = *(const float4v*)(ph + idx);
            float4v p1 = *(const float4v*)(ph + idx + 4);
            float4v s0 = 0.5f * (i0 + p0);
            float4v s1 = 0.5f * (i1 + p1);
            *(short8*)(img_bf + idx) = packv(i0, i1);
            *(short8*)(ph_bf + idx)  = packv(p0, p1);
            *(short8*)(sh_bf + idx)  = packv(s0, s1);
        } else {
            short8 z = (short8){0,0,0,0,0,0,0,0};
            *(short8*)(img_bf + idx) = z;
            *(short8*)(ph_bf + idx)  = z;
            *(short8*)(sh_bf + idx)  = z;
        }
    } else {
        const int t = (bid - EMBED_BLOCKS) * 256 + threadIdx.x;   // 0..98303
        const int mat = t >> 15;
        const size_t idx = (size_t)(t & 32767) * 8;
        const float* src = (mat == 0) ? Wi : ((mat == 1) ? Wp : Ws);
        unsigned short* dst = (mat == 0) ? Wi_bf : ((mat == 1) ? Wp_bf : Ws_bf);
        float4v a = *(const float4v*)(src + idx);
        float4v b = *(const float4v*)(src + idx + 4);
        *(short8*)(dst + idx) = packv(a, b);
    }
}

// ---- K2: fused triple GEMM + tanh + joint combine + Frobenius sums ----
// XCD-aware swizzle: dispatch round-robins blocks over 8 XCDs (bid % 8).
// Give each XCD a contiguous slab of 49 row-strips, iterating col-tiles
// fastest, so the 8 col-blocks sharing an A-strip are co-resident on ONE
// XCD: A-strip fetched once into that L2, then 8x L2 hits; B (1.5 MB bf16)
// stays L2-resident. Pure permutation -> correctness-neutral (G16).
__global__ __launch_bounds__(256, 2) void fused_mma2(
    const unsigned short* __restrict__ img_bf, const unsigned short* __restrict__ ph_bf,
    const unsigned short* __restrict__ sh_bf,
    const unsigned short* __restrict__ Wi_bf, const unsigned short* __restrict__ Wp_bf,
    const unsigned short* __restrict__ Ws_bf,
    const float* __restrict__ bs, const float* __restrict__ bi, const float* __restrict__ bp,
    float* __restrict__ out, float* __restrict__ sums)
{
    const int bid  = blockIdx.x;
    const int xcd  = bid & 7;
    const int u    = bid >> 3;          // 0..391
    const int col  = u & 7;             // col-tile, fastest within XCD
    const int s    = u >> 3;            // 0..48, strip within slab
    const int strip = xcd * STRIPS_PER_XCD + s;
    if (strip >= N_STRIPS) return;

    const int e0 = col * BN;
    const int n0 = strip * BM;

    // unpadded layout required: global_load_lds writes wave-uniform base + lane*16
    __shared__ __align__(16) unsigned short sA[3][BM][BK];  // 24 KB
    __shared__ __align__(16) unsigned short sB[3][BN][BK];  // 12 KB

    const int tid  = threadIdx.x;
    const int lane = tid & 63;
    const int wid  = tid >> 6;
    const int wm   = wid & 1;       // 64-row half
    const int wn   = wid >> 1;      // 32-col half
    const int l15  = lane & 15;
    const int quad = lane >> 4;

    const unsigned short* Amat[3] = { img_bf, ph_bf, sh_bf };
    const unsigned short* Bmat[3] = { Wi_bf, Wp_bf, Ws_bf };

    const int lrow = lane >> 2;        // 0..15 (row within 16-row chunk)
    const int lcol = (lane & 3) * 8;   // elem offset within 32-elem row

    float4v acc[3][4][2];
#pragma unroll
    for (int m = 0; m < 3; ++m)
#pragma unroll
        for (int i = 0; i < 4; ++i)
#pragma unroll
            for (int j = 0; j < 2; ++j)
                acc[m][i][j] = (float4v){0.f, 0.f, 0.f, 0.f};

#pragma unroll 1
    for (int kb = 0; kb < DIM / BK; ++kb) {
        const int k0 = kb * BK;

        // 36 wave-chunks of 1 KB (24 for A: 3 mats x 8, 12 for B: 3 mats x 4),
        // 9 per wave, DMA'd straight to LDS.
#pragma unroll
        for (int t = 0; t < 9; ++t) {
            const int c = wid * 9 + t;
            if (c < 24) {
                const int mat = c >> 3, sub = c & 7;
                const unsigned short* g =
                    Amat[mat] + (size_t)(n0 + sub * 16 + lrow) * DIM + k0 + lcol;
                async_ld16(g, &sA[mat][sub * 16][0]);
            } else {
                const int cc = c - 24;
                const int mat = cc >> 2, sub = cc & 3;
                const unsigned short* g =
                    Bmat[mat] + (size_t)(e0 + sub * 16 + lrow) * DIM + k0 + lcol;
                async_ld16(g, &sB[mat][sub * 16][0]);
            }
        }

        __syncthreads();

#pragma unroll
        for (int mat = 0; mat < 3; ++mat) {
            short8 a[4], b[2];
#pragma unroll
            for (int i = 0; i < 4; ++i)
                a[i] = *(const short8*)&sA[mat][wm * 64 + i * 16 + l15][quad * 8];
#pragma unroll
            for (int j = 0; j < 2; ++j)
                b[j] = *(const short8*)&sB[mat][wn * 32 + j * 16 + l15][quad * 8];
#pragma unroll
            for (int i = 0; i < 4; ++i)
#pragma unroll
                for (int j = 0; j < 2; ++j)
                    acc[mat][i][j] = __builtin_amdgcn_mfma_f32_16x16x32_bf16(
                        a[i], b[j], acc[mat][i][j], 0, 0, 0);
        }

        __syncthreads();
    }

    // ---- epilogue ----
    float s_i = 0.f, s_p = 0.f, s_s = 0.f;
#pragma unroll
    for (int i = 0; i < 4; ++i) {
#pragma unroll
        for (int j = 0; j < 2; ++j) {
            const int c = e0 + wn * 32 + j * 16 + l15;
            const float bii = bi[c], bpp = bp[c], bss = bs[c];
            const int rbase = n0 + wm * 64 + i * 16 + quad * 4;
#pragma unroll
            for (int r = 0; r < 4; ++r) {
                const int nrow = rbase + r;
                const float ia = fast_tanh(acc[0][i][j][r] + bii);
                const float pa = fast_tanh(acc[1][i][j][r] + bpp);
                const float sa = fast_tanh(acc[2][i][j][r] + bss);
                if (nrow < N_ROWS) {
                    const size_t off = (size_t)nrow * DIM + c;
                    const float ie = bf2f(img_bf[off]);
                    const float pe = bf2f(ph_bf[off]);
                    const float se = 0.5f * (ie + pe);
                    out[off] = sa * se + ia * ie + pa * pe;
                    s_i += ia * ia; s_p += pa * pa; s_s += sa * sa;
                }
            }
        }
    }

#pragma unroll
    for (int off = 32; off > 0; off >>= 1) {
        s_i += __shfl_down(s_i, off);
        s_p += __shfl_down(s_p, off);
        s_s += __shfl_down(s_s, off);
    }
    if (lane == 0) {
        atomicAdd(&sums[0], s_i);
        atomicAdd(&sums[1], s_p);
        atomicAdd(&sums[2], s_s);
    }
}

__global__ void finalize(const float* __restrict__ sums, float* __restrict__ wout) {
    if (threadIdx.x == 0) {
        const float inv_sh = 1.0f / sums[2];
        const float is = sums[0] * inv_sh;
        const float ps = sums[1] * inv_sh;
        const float m  = fmaxf(is, ps);
        const float ei = expf(is - m), ep = expf(ps - m);
        const float inv = 1.0f / (ei + ep);
        wout[0] = ei * inv;
        wout[1] = ep * inv;
    }
}

extern "C" void kernel_launch(void* const* d_in, const int* in_sizes, int n_in,
                              void* d_out, int out_size, void* d_ws, size_t ws_size,
                              hipStream_t stream) {
    const float* img = (const float*)d_in[0];
    const float* ph  = (const float*)d_in[1];
    const float* Ws  = (const float*)d_in[2];
    const float* bs  = (const float*)d_in[3];
    const float* Wi  = (const float*)d_in[4];
    const float* bi  = (const float*)d_in[5];
    const float* Wp  = (const float*)d_in[6];
    const float* bp  = (const float*)d_in[7];
    float* out  = (float*)d_out;
    float* sums = (float*)d_ws;

    const size_t embed_elems = (size_t)NPAD * DIM;
    const size_t w_elems = (size_t)DIM * DIM;

    unsigned short* base   = (unsigned short*)((char*)d_ws + 256);
    unsigned short* img_bf = base;
    unsigned short* ph_bf  = img_bf + embed_elems;
    unsigned short* sh_bf  = ph_bf + embed_elems;
    unsigned short* Wi_bf  = sh_bf + embed_elems;
    unsigned short* Wp_bf  = Wi_bf + w_elems;
    unsigned short* Ws_bf  = Wp_bf + w_elems;

    convert_all<<<EMBED_BLOCKS + W_BLOCKS, 256, 0, stream>>>(
        img, ph, Wi, Wp, Ws, img_bf, ph_bf, sh_bf, Wi_bf, Wp_bf, Ws_bf, sums);

    // 8 xcds x 49 strips x 8 cols = 3136 blocks (8 no-ops where strip >= 391)
    fused_mma2<<<8 * STRIPS_PER_XCD * 8, 256, 0, stream>>>(
        img_bf, ph_bf, sh_bf, Wi_bf, Wp_bf, Ws_bf, bs, bi, bp, out, sums);

    finalize<<<1, 64, 0, stream>>>(sums, out + (size_t)N_ROWS * DIM);
}